// Round 1
// 303.458 us; speedup vs baseline: 1.0332x; 1.0332x over previous
//
#include <hip/hip_runtime.h>
#include <cmath>
#include <cstdint>

typedef __bf16 bf16;
typedef __bf16 bf16x8 __attribute__((ext_vector_type(8)));
typedef __bf16 bf16x4 __attribute__((ext_vector_type(4)));
typedef float f32x4 __attribute__((ext_vector_type(4)));

#define SDIM 2048
#define DDIM 2048
#define NQKV 2304   // H*DH + 2*DH
#define DH   128

__device__ __forceinline__ void glds16(const bf16* g, bf16* l) {
    __builtin_amdgcn_global_load_lds(
        (const __attribute__((address_space(1))) void*)g,
        (__attribute__((address_space(3))) void*)l, 16, 0, 0);
}

// raw barrier (NO implicit s_waitcnt vmcnt(0) drain, unlike __syncthreads) with
// compiler-level memory fences so LDS reads / glds can't be moved across it.
#define MEMFENCE() asm volatile("" ::: "memory")
#define SBAR() do { MEMFENCE(); __builtin_amdgcn_s_barrier(); MEMFENCE(); } while (0)

// ---------------- fused prep: cast x->bf16 + 4 weight transposes, ONE launch ----------------
__global__ __launch_bounds__(256) void prep_kernel(const float* __restrict__ x,
                                                   const float* __restrict__ Wq,
                                                   const float* __restrict__ Wk,
                                                   const float* __restrict__ Wv,
                                                   const float* __restrict__ Wo,
                                                   bf16* __restrict__ xb,
                                                   bf16* __restrict__ Wqkv_t,
                                                   bf16* __restrict__ Wo_t) {
    __shared__ float tile[32][33];
    int bx = blockIdx.x;
    if (bx < 8192) {
        int i = bx * 256 + threadIdx.x;
        float4 v = reinterpret_cast<const float4*>(x)[i];
        bf16x4 o;
        o[0] = (bf16)v.x; o[1] = (bf16)v.y; o[2] = (bf16)v.z; o[3] = (bf16)v.w;
        reinterpret_cast<bf16x4*>(xb)[i] = o;
        return;
    }
    bx -= 8192;
    const float* src; bf16* dst; int srcN; int t;
    if (bx < 4096)      { src = Wq; dst = Wqkv_t;                      srcN = 2048; t = bx; }
    else if (bx < 4352) { src = Wk; dst = Wqkv_t + (size_t)2048*2048;  srcN = 128;  t = bx - 4096; }
    else if (bx < 4608) { src = Wv; dst = Wqkv_t + (size_t)2176*2048;  srcN = 128;  t = bx - 4352; }
    else                { src = Wo; dst = Wo_t;                        srcN = 2048; t = bx - 4608; }
    const int srcK = 2048;
    int ntx = srcN >> 5;
    int n0 = (t % ntx) * 32, k0 = (t / ntx) * 32;
    int tx = threadIdx.x & 31;
    int ty = threadIdx.x >> 5;           // 0..7
    for (int i = 0; i < 4; i++)
        tile[ty + i*8][tx] = src[(size_t)(k0 + ty + i*8) * srcN + n0 + tx];
    __syncthreads();
    for (int i = 0; i < 4; i++)
        dst[(size_t)(n0 + ty + i*8) * srcK + k0 + tx] = (bf16)tile[tx][ty + i*8];
}

// ---------------- transpose V columns of QKV -> Vt[b][128][2048] bf16 ----------------
__global__ __launch_bounds__(256) void vtrans_kernel(const bf16* __restrict__ QKV,
                                                     bf16* __restrict__ Vt) {
    __shared__ bf16 tile[32][33];
    int tx = threadIdx.x & 31;
    int ty = threadIdx.x >> 5;           // 0..7
    int d0 = blockIdx.x * 32;
    int s0 = blockIdx.y * 32;
    int b  = blockIdx.z;
    for (int i = 0; i < 4; i++)
        tile[ty + i*8][tx] = QKV[((size_t)b * SDIM + s0 + ty + i*8) * NQKV + 2176 + d0 + tx];
    __syncthreads();
    for (int i = 0; i < 4; i++)
        Vt[((size_t)b * DH + d0 + ty + i*8) * SDIM + s0 + tx] = tile[tx][ty + i*8];
}

// ---------------- 256x256 / BK=64 / 8-wave / 8-phase GEMM (T2+T3+T4+T5) ----------------
// C = A(MxK rm) * Bt^T.  K fixed = 2048 (NT = 32 K-tiles of 64).
// LDS 128 KiB: A/B each 2 bufs x 2 k-halves x [256 rows][32 k] bf16 (16 KiB/half).
// Chunk swizzle: LDS[r][cc] holds global chunk cc ^ ((r>>1)&3)  -> ds_read_b128 2-way (free).
// Per K-tile 4 phases: {ds_read regs | stage 1 half | s_barrier | 16 MFMA (setprio) | s_barrier}.
// Stage schedule per tile t: p1:(t+1,A,kh1) p2:(t+1,B,kh1) p3:(t+2,A,kh0) p4:(t+2,B,kh0).
// Counted waits: vmcnt(8) end of p2, vmcnt(4) end of p4 (drain 0 only at final tiles).
template<int WRITE_F32>
__global__ __launch_bounds__(512, 2) void gemm8_kernel(const bf16* __restrict__ A,
                                                       const bf16* __restrict__ Bt,
                                                       void* __restrict__ Cout,
                                                       const float* __restrict__ bias,
                                                       int N) {
    constexpr int K  = 2048;
    constexpr int NT = 32;               // K / 64
    __shared__ bf16 smem[65536];         // [A: 0..32767][B: 32768..65535] elems

    const int tid  = threadIdx.x;
    const int wave = tid >> 6, lane = tid & 63;
    const int quad = lane >> 4, l15 = lane & 15;
    const int wm = wave >> 2, wn = wave & 3;        // 2 x 4 waves
    const int tm = blockIdx.x * 256, tn = blockIdx.y * 256;

    // ---- staging geometry: chunk c = wave*128 + i*64 + lane, row = c>>2, pos = c&3 ----
    const int r0 = wave * 32 + (lane >> 2);            // row for i=0
    const int cs = (lane & 3) ^ ((lane >> 3) & 3);     // source chunk ((r>>1)&3 swizzle)
    const bf16* Ag = A  + (size_t)(tm + r0) * K + cs * 8;
    const bf16* Bg = Bt + (size_t)(tn + r0) * K + cs * 8;
    bf16* Asl = smem + wave * 1024;                    // wave-uniform dest base (i=0)
    bf16* Bsl = smem + 32768 + wave * 1024;

    auto STAGE_A = [&](int t, int kh) {
        if (t < NT) {
            const bf16* s = Ag + t * 64 + kh * 32;
            bf16* d = Asl + (t & 1) * 16384 + kh * 8192;
            glds16(s, d);
            glds16(s + 16 * K, d + 512);
        }
    };
    auto STAGE_B = [&](int t, int kh) {
        if (t < NT) {
            const bf16* s = Bg + t * 64 + kh * 32;
            bf16* d = Bsl + (t & 1) * 16384 + kh * 8192;
            glds16(s, d);
            glds16(s + 16 * K, d + 512);
        }
    };

    // ---- ds_read fragment offsets (swizzled chunk = quad ^ ((row>>1)&3)) ----
    const int rsw  = (l15 >> 1) & 3;
    const int aoff = (wm * 128 + l15) * 32 + ((quad ^ rsw) * 8);
    const int boff = (wn * 64  + l15) * 32 + ((quad ^ rsw) * 8);

    f32x4 acc[8][4];
#pragma unroll
    for (int m = 0; m < 8; m++)
#pragma unroll
        for (int n = 0; n < 4; n++) acc[m][n] = (f32x4)0.0f;

    // ---- prologue: tile0 (4 halves) + tile1 kh0 (2 halves); keep tile1 in flight ----
    STAGE_A(0, 0); STAGE_B(0, 0);
    STAGE_A(0, 1); STAGE_B(0, 1);
    STAGE_A(1, 0); STAGE_B(1, 0);
    asm volatile("s_waitcnt vmcnt(4)" ::: "memory");
    SBAR();

    bf16x8 av[4], bv[4];
    for (int t = 0; t < NT; ++t) {
        const int buf = t & 1;
        const bf16* Sa = smem + buf * 16384;
        const bf16* Sb = smem + 32768 + buf * 16384;

        // ---- phase 1: kh0, m0-3 x n0-3 ----
#pragma unroll
        for (int m = 0; m < 4; m++) av[m] = *reinterpret_cast<const bf16x8*>(Sa + aoff + m * 512);
#pragma unroll
        for (int n = 0; n < 4; n++) bv[n] = *reinterpret_cast<const bf16x8*>(Sb + boff + n * 512);
        STAGE_A(t + 1, 1);
        SBAR();
        __builtin_amdgcn_s_setprio(1);
#pragma unroll
        for (int m = 0; m < 4; m++)
#pragma unroll
            for (int n = 0; n < 4; n++)
                acc[m][n] = __builtin_amdgcn_mfma_f32_16x16x32_bf16(av[m], bv[n], acc[m][n], 0, 0, 0);
        __builtin_amdgcn_s_setprio(0);
        SBAR();

        // ---- phase 2: kh0, m4-7 x n0-3 (reuse bv) ----
#pragma unroll
        for (int m = 0; m < 4; m++) av[m] = *reinterpret_cast<const bf16x8*>(Sa + aoff + 2048 + m * 512);
        STAGE_B(t + 1, 1);
        SBAR();
        __builtin_amdgcn_s_setprio(1);
#pragma unroll
        for (int m = 0; m < 4; m++)
#pragma unroll
            for (int n = 0; n < 4; n++)
                acc[4 + m][n] = __builtin_amdgcn_mfma_f32_16x16x32_bf16(av[m], bv[n], acc[4 + m][n], 0, 0, 0);
        __builtin_amdgcn_s_setprio(0);
        if (t + 1 < NT) { asm volatile("s_waitcnt vmcnt(8)" ::: "memory"); }
        else            { asm volatile("s_waitcnt vmcnt(0)" ::: "memory"); }
        SBAR();

        // ---- phase 3: kh1, m0-3 x n0-3 ----
#pragma unroll
        for (int m = 0; m < 4; m++) av[m] = *reinterpret_cast<const bf16x8*>(Sa + 8192 + aoff + m * 512);
#pragma unroll
        for (int n = 0; n < 4; n++) bv[n] = *reinterpret_cast<const bf16x8*>(Sb + 8192 + boff + n * 512);
        STAGE_A(t + 2, 0);
        SBAR();
        __builtin_amdgcn_s_setprio(1);
#pragma unroll
        for (int m = 0; m < 4; m++)
#pragma unroll
            for (int n = 0; n < 4; n++)
                acc[m][n] = __builtin_amdgcn_mfma_f32_16x16x32_bf16(av[m], bv[n], acc[m][n], 0, 0, 0);
        __builtin_amdgcn_s_setprio(0);
        SBAR();

        // ---- phase 4: kh1, m4-7 x n0-3 ----
#pragma unroll
        for (int m = 0; m < 4; m++) av[m] = *reinterpret_cast<const bf16x8*>(Sa + 8192 + aoff + 2048 + m * 512);
        STAGE_B(t + 2, 0);
        SBAR();
        __builtin_amdgcn_s_setprio(1);
#pragma unroll
        for (int m = 0; m < 4; m++)
#pragma unroll
            for (int n = 0; n < 4; n++)
                acc[4 + m][n] = __builtin_amdgcn_mfma_f32_16x16x32_bf16(av[m], bv[n], acc[4 + m][n], 0, 0, 0);
        __builtin_amdgcn_s_setprio(0);
        if (t + 2 < NT) { asm volatile("s_waitcnt vmcnt(4)" ::: "memory"); }
        else            { asm volatile("s_waitcnt vmcnt(0)" ::: "memory"); }
        SBAR();
    }

    // ---- epilogue: wave writes its 128x64 block ----
#pragma unroll
    for (int m = 0; m < 8; m++)
#pragma unroll
        for (int n = 0; n < 4; n++)
#pragma unroll
            for (int r = 0; r < 4; r++) {
                int row = tm + wm * 128 + m * 16 + quad * 4 + r;
                int col = tn + wn * 64 + n * 16 + l15;
                float v = acc[m][n][r];
                if (WRITE_F32)
                    reinterpret_cast<float*>(Cout)[(size_t)row * N + col] = v + bias[col];
                else
                    reinterpret_cast<bf16*>(Cout)[(size_t)row * N + col] = (bf16)v;
            }
}

// ---------------- causal flash attention v7: MQA head-sharing + async DMA staging ----------------
#define FPLD 72     // per-wave P stride [16 heads][64 keys + 8]

__global__ __launch_bounds__(512) void flash_kernel(const bf16* __restrict__ QKV,
                                                    const bf16* __restrict__ Vt,
                                                    bf16* __restrict__ attn) {
    __shared__ bf16 KVS[16384];          // Ks (8192 elems) | Vts (8192 elems); reused for out
    __shared__ bf16 Ps[8 * 16 * FPLD];   // per-wave P tile
    bf16* Ks  = KVS;
    bf16* Vts = KVS + 8192;

    const int tid  = threadIdx.x;
    const int wave = tid >> 6, lane = tid & 63;
    const int quad = lane >> 4, l15 = lane & 15;
    const int bx = blockIdx.x;
    const int qs = 255 - (bx >> 1);   // LPT: largest key ranges first
    const int b  = bx & 1;
    const int q  = qs * 8 + wave;     // this wave's query row
    const size_t rowbase = (size_t)b * SDIM;
    const bf16* Vtb = Vt + (size_t)b * DH * SDIM;
    const float scale = 0.088388347648318447f;  // 1/sqrt(128)

    const int s0 = wave, s1 = wave + 8;
    const int krow0 = s0*4 + (lane >> 4), krow1 = s1*4 + (lane >> 4);
    const int kchunk = lane & 15;
    const bf16* kg0 = QKV + (rowbase + krow0) * NQKV + 2048 + ((kchunk ^ (krow0 & 15)) * 8);
    const bf16* kg1 = QKV + (rowbase + krow1) * NQKV + 2048 + ((kchunk ^ (krow1 & 15)) * 8);
    bf16* kl0 = Ks + s0 * 512;   // wave-uniform LDS base
    bf16* kl1 = Ks + s1 * 512;
    const int vrow0 = s0*8 + (lane >> 3), vrow1 = s1*8 + (lane >> 3);
    const int vchunk = lane & 7;
    const bf16* vg0 = Vtb + (size_t)vrow0 * SDIM + ((vchunk ^ (vrow0 & 7)) * 8);
    const bf16* vg1 = Vtb + (size_t)vrow1 * SDIM + ((vchunk ^ (vrow1 & 7)) * 8);
    bf16* vl0 = Vts + s0 * 512;
    bf16* vl1 = Vts + s1 * 512;

    bf16x8 qf[4];
    {
        const bf16* qp = QKV + (rowbase + q) * NQKV + l15 * DH + quad * 8;
        for (int kk = 0; kk < 4; kk++)
            qf[kk] = *reinterpret_cast<const bf16x8*>(qp + kk * 32);
    }
    float l_s[4] = {0.0f, 0.0f, 0.0f, 0.0f};
    f32x4 acc[8];
    for (int d = 0; d < 8; d++) acc[d] = (f32x4)0.0f;

    const int ntiles = (qs >> 3) + 1;   // block-uniform (barrier-legal)
    bf16* Pw = Ps + wave * (16 * FPLD);

    const bf16* kp0 = kg0; const bf16* kp1 = kg1;
    const bf16* vp0 = vg0; const bf16* vp1 = vg1;

    for (int t = 0; t < ntiles; t++) {
        const int key0 = t * 64;
        __syncthreads();
        glds16(kp0, kl0); glds16(kp1, kl1);
        glds16(vp0, vl0); glds16(vp1, vl1);
        kp0 += 64 * NQKV; kp1 += 64 * NQKV; vp0 += 64; vp1 += 64;
        __syncthreads();

        // QK: C[row=head][col=key]; swizzled K reads (conflict-free b128)
        f32x4 sc[4];
        for (int c = 0; c < 4; c++) sc[c] = (f32x4)0.0f;
        for (int c = 0; c < 4; c++)
            for (int kk = 0; kk < 4; kk++) {
                int j = (kk*4 + quad) ^ l15;     // swizzled 16B-chunk index
                bf16x8 kf = *reinterpret_cast<const bf16x8*>(
                    Ks + (c*16 + l15) * 128 + j * 8);
                sc[c] = __builtin_amdgcn_mfma_f32_16x16x32_bf16(qf[kk], kf, sc[c], 0, 0, 0);
            }

        const bool tail = (key0 + 63 > q);   // wave-uniform
        for (int c = 0; c < 4; c++)
            for (int r = 0; r < 4; r++) {
                float p;
                if (tail && (key0 + c*16 + l15 > q)) p = 0.0f;
                else p = __expf(sc[c][r] * scale);
                l_s[r] += p;
                Pw[(quad*4 + r) * FPLD + c*16 + l15] = (bf16)p;
            }

        // PV: A[m=head][k=key] from Pw, B[n=d][k=key] from swizzled Vts
        for (int kk2 = 0; kk2 < 2; kk2++) {
            bf16x8 pf = *reinterpret_cast<const bf16x8*>(Pw + l15 * FPLD + kk2*32 + quad*8);
            for (int dd = 0; dd < 8; dd++) {
                int d = dd*16 + l15;
                int j = (kk2*4 + quad) ^ (l15 & 7);
                bf16x8 vf = *reinterpret_cast<const bf16x8*>(Vts + d * 64 + j * 8);
                acc[dd] = __builtin_amdgcn_mfma_f32_16x16x32_bf16(pf, vf, acc[dd], 0, 0, 0);
            }
        }
    }

    __syncthreads();   // all waves done with Ks/Vts -> reuse KVS for output staging

    for (int d = 1; d < 16; d <<= 1)
        for (int r = 0; r < 4; r++) l_s[r] += __shfl_xor(l_s[r], d);

    bf16* Ow = KVS + wave * 2048;
    for (int r = 0; r < 4; r++) {
        float inv = 1.0f / l_s[r];
        for (int d = 0; d < 8; d++)
            Ow[(quad*4 + r) * 128 + d*16 + l15] = (bf16)(acc[d][r] * inv);
    }
    const int orow = lane >> 2;          // head 0..15
    const int ocol = (lane & 3) * 8;
    bf16* ob = attn + (rowbase + q) * (size_t)DDIM;
    for (int it = 0; it < 4; it++)
        *reinterpret_cast<uint4*>(ob + orow * DH + ocol + it*32) =
            *reinterpret_cast<const uint4*>(Ow + orow * 128 + ocol + it*32);
}

extern "C" void kernel_launch(void* const* d_in, const int* in_sizes, int n_in,
                              void* d_out, int out_size, void* d_ws, size_t ws_size,
                              hipStream_t stream) {
    const float* x  = (const float*)d_in[0];
    // d_in[1] = mask: exactly causal tril, applied analytically in flash_kernel
    const float* Wq = (const float*)d_in[2];
    const float* Wk = (const float*)d_in[3];
    const float* Wv = (const float*)d_in[4];
    const float* Wo = (const float*)d_in[5];
    const float* bo = (const float*)d_in[6];
    float* out = (float*)d_out;

    char* ws = (char*)d_ws;
    bf16* xb     = (bf16*)(ws);                              // 4096x2048      = 16777216 B
    bf16* Wqkv_t = (bf16*)(ws + 16777216);                   // 2304x2048      =  9437184 B
    bf16* Wo_t   = (bf16*)(ws + 26214400);                   // 2048x2048      =  8388608 B
    bf16* QKV    = (bf16*)(ws + 34603008);                   // 4096x2304      = 18874368 B
    bf16* attn   = (bf16*)(ws + 53477376);                   // 4096x2048      = 16777216 B
    bf16* Vtb    = (bf16*)(ws + 70254592);                   // 2x128x2048     =  1048576 B
    (void)ws_size; (void)in_sizes; (void)n_in; (void)out_size;

    prep_kernel<<<16896, 256, 0, stream>>>(x, Wq, Wk, Wv, Wo, xb, Wqkv_t, Wo_t);
    gemm8_kernel<0><<<dim3(16, 9), 512, 0, stream>>>(xb, Wqkv_t, (void*)QKV, nullptr, 2304);
    vtrans_kernel<<<dim3(4, 64, 2), 256, 0, stream>>>(QKV, Vtb);
    flash_kernel<<<512, 512, 0, stream>>>(QKV, Vtb, attn);
    gemm8_kernel<1><<<dim3(16, 8), 512, 0, stream>>>(attn, Wo_t, (void*)out, bo, 2048);
}